// Round 1
// baseline (41037.939 us; speedup 1.0000x reference)
//
#include <hip/hip_runtime.h>
#include <math.h>

#define D 128
#define NH 16
#define HD 8
#define NLAYER 16
#define V 17
#define L 1024
#define BOSX 16
#define NHEAL 31

static __device__ __forceinline__ float waveSum(float v) {
#pragma unroll
  for (int o = 32; o > 0; o >>= 1) v += __shfl_down(v, o, 64);
  return v;
}

// ---- lat init: lat[0]=BOS, lat[1..1024]=tokens ----
__global__ void kInit(const int* __restrict__ tokens, int* __restrict__ lat) {
  int i = blockIdx.x * blockDim.x + threadIdx.x;
  if (i == 0) lat[0] = BOSX;
  if (i < L) lat[i + 1] = tokens[i];
}

// ---- embed rows [cs,ce]: h[row] = emb[lat[row]] + pos[row] ----
__global__ void kEmbedRows(const int* __restrict__ lat, const float* __restrict__ emb,
                           const float* __restrict__ pos, float* __restrict__ h,
                           const int* __restrict__ bounds, int bk) {
  int cs, ce;
  if (bk >= 0) { cs = bounds[2 * bk]; ce = bounds[2 * bk + 1]; }
  else { cs = 0; ce = L - 1; }
  int t = threadIdx.x;
  for (int row = cs + (int)blockIdx.x; row <= ce; row += (int)gridDim.x) {
    if (t < D) h[row * D + t] = emb[lat[row] * D + t] + pos[row * D + t];
  }
}

// ---- stage A: x=LN1(h[row]); qkv = x@wqkv + b; write qbuf,kc,vc ----
__global__ void kA(const float* __restrict__ h, const float* __restrict__ ln_s,
                   const float* __restrict__ ln_b, const float* __restrict__ wqkv,
                   const float* __restrict__ bqkv, float* __restrict__ qbuf,
                   float* __restrict__ kc, float* __restrict__ vc,
                   const int* __restrict__ bounds, int bk) {
  __shared__ float x[D];
  __shared__ float red[8];
  int cs, ce;
  if (bk >= 0) { cs = bounds[2 * bk]; ce = bounds[2 * bk + 1]; }
  else { cs = 0; ce = L - 1; }
  int t = threadIdx.x;
  for (int row = cs + (int)blockIdx.x; row <= ce; row += (int)gridDim.x) {
    float v0 = (t < D) ? h[row * D + t] : 0.f;
    float ws = waveSum(v0);
    if ((t & 63) == 0) red[t >> 6] = ws;
    __syncthreads();
    float mean = (red[0] + red[1]) * (1.f / 128.f);
    float dv = (t < D) ? (v0 - mean) : 0.f;
    float ws2 = waveSum(dv * dv);
    if ((t & 63) == 0) red[4 + (t >> 6)] = ws2;
    __syncthreads();
    float rstd = rsqrtf((red[4] + red[5]) * (1.f / 128.f) + 1e-5f);
    if (t < D) x[t] = dv * rstd * ln_s[t] + ln_b[t];
    __syncthreads();
    for (int j = t; j < 3 * D; j += 256) {
      float acc = 0.f;
#pragma unroll 8
      for (int d = 0; d < D; ++d) acc += x[d] * wqkv[d * (3 * D) + j];
      acc += bqkv[j];
      if (j < D) qbuf[row * D + j] = acc;
      else if (j < 2 * D) kc[row * D + (j - D)] = acc;
      else vc[row * D + (j - 2 * D)] = acc;
    }
    __syncthreads();
  }
}

// ---- stage B: attention + proj + residual + LN2 + FF + residual, per row ----
__global__ void kB(float* __restrict__ h, const float* __restrict__ qbuf,
                   const float* __restrict__ kc, const float* __restrict__ vc,
                   const float* __restrict__ wo, const float* __restrict__ bo,
                   const float* __restrict__ ln_s, const float* __restrict__ ln_b,
                   const float* __restrict__ w1, const float* __restrict__ b1,
                   const float* __restrict__ w2, const float* __restrict__ b2,
                   const int* __restrict__ bounds, int bk) {
  __shared__ float pm[16][16];
  __shared__ float psum[16][16];
  __shared__ float pacc[16][16][HD];
  __shared__ float obuf[D];
  __shared__ float hrow[D];
  __shared__ float xn[D];
  __shared__ float f[4 * D];
  __shared__ float red[8];
  int cs, ce;
  if (bk >= 0) { cs = bounds[2 * bk]; ce = bounds[2 * bk + 1]; }
  else { cs = 0; ce = L - 1; }
  int t = threadIdx.x;
  int head = t >> 4, lane = t & 15;
  for (int row = cs + (int)blockIdx.x; row <= ce; row += (int)gridDim.x) {
    // --- attention (16 threads per head, online softmax partials) ---
    float q[HD];
#pragma unroll
    for (int e = 0; e < HD; ++e) q[e] = qbuf[row * D + head * HD + e];
    float m = -INFINITY, sum = 0.f, acc[HD];
#pragma unroll
    for (int e = 0; e < HD; ++e) acc[e] = 0.f;
    for (int key = lane; key <= row; key += 16) {
      const float* kp = kc + key * D + head * HD;
      float sc = 0.f;
#pragma unroll
      for (int e = 0; e < HD; ++e) sc += q[e] * kp[e];
      sc *= 0.35355339059327376f;
      if (sc > m) {
        float c = expf(m - sc);
        sum *= c;
#pragma unroll
        for (int e = 0; e < HD; ++e) acc[e] *= c;
        m = sc;
      }
      float p = expf(sc - m);
      sum += p;
      const float* vp = vc + key * D + head * HD;
#pragma unroll
      for (int e = 0; e < HD; ++e) acc[e] += p * vp[e];
    }
    pm[head][lane] = m;
    psum[head][lane] = sum;
#pragma unroll
    for (int e = 0; e < HD; ++e) pacc[head][lane][e] = acc[e];
    __syncthreads();
    if (t < 16) {
      float mm = -INFINITY;
      for (int l = 0; l < 16; ++l) mm = fmaxf(mm, pm[t][l]);
      float ss = 0.f;
      float o[HD];
#pragma unroll
      for (int e = 0; e < HD; ++e) o[e] = 0.f;
      for (int l = 0; l < 16; ++l) {
        if (psum[t][l] > 0.f) {
          float c = expf(pm[t][l] - mm);
          ss += psum[t][l] * c;
#pragma unroll
          for (int e = 0; e < HD; ++e) o[e] += pacc[t][l][e] * c;
        }
      }
      float inv = 1.f / ss;
#pragma unroll
      for (int e = 0; e < HD; ++e) obuf[t * HD + e] = o[e] * inv;
    }
    __syncthreads();
    // --- proj + residual ---
    if (t < D) {
      float a = 0.f;
#pragma unroll 8
      for (int d = 0; d < D; ++d) a += obuf[d] * wo[d * D + t];
      float hv = h[row * D + t] + a + bo[t];
      hrow[t] = hv;
      h[row * D + t] = hv;
    }
    __syncthreads();
    // --- LN2 ---
    float v0 = (t < D) ? hrow[t] : 0.f;
    float ws = waveSum(v0);
    if ((t & 63) == 0) red[t >> 6] = ws;
    __syncthreads();
    float mean = (red[0] + red[1]) * (1.f / 128.f);
    float dv = (t < D) ? (v0 - mean) : 0.f;
    float ws2 = waveSum(dv * dv);
    if ((t & 63) == 0) red[4 + (t >> 6)] = ws2;
    __syncthreads();
    float rstd = rsqrtf((red[4] + red[5]) * (1.f / 128.f) + 1e-5f);
    if (t < D) xn[t] = dv * rstd * ln_s[t] + ln_b[t];
    __syncthreads();
    // --- FF1 + gelu ---
    for (int j = t; j < 4 * D; j += 256) {
      float a = 0.f;
#pragma unroll 8
      for (int d = 0; d < D; ++d) a += xn[d] * w1[d * (4 * D) + j];
      a += b1[j];
      float c = 0.7978845608028654f * (a + 0.044715f * a * a * a);
      f[j] = 0.5f * a * (1.f + tanhf(c));
    }
    __syncthreads();
    // --- FF2 + residual ---
    if (t < D) {
      float a = 0.f;
#pragma unroll 8
      for (int d = 0; d < 4 * D; ++d) a += f[d] * w2[d * D + t];
      h[row * D + t] = hrow[t] + a + b2[t];
    }
    __syncthreads();
  }
}

// ---- head: logits[row] = LNf(h[row]) @ head_w + head_b ----
__global__ void kHead(const float* __restrict__ h, const float* __restrict__ lnf_s,
                      const float* __restrict__ lnf_b, const float* __restrict__ hw,
                      const float* __restrict__ hb, float* __restrict__ logits,
                      const int* __restrict__ bounds, int bk) {
  __shared__ float xn[D];
  __shared__ float red[8];
  int cs, ce;
  if (bk >= 0) { cs = bounds[2 * bk]; ce = bounds[2 * bk + 1]; }
  else { cs = 0; ce = L - 1; }
  int t = threadIdx.x;
  for (int row = cs + (int)blockIdx.x; row <= ce; row += (int)gridDim.x) {
    float v0 = (t < D) ? h[row * D + t] : 0.f;
    float ws = waveSum(v0);
    if ((t & 63) == 0) red[t >> 6] = ws;
    __syncthreads();
    float mean = (red[0] + red[1]) * (1.f / 128.f);
    float dv = (t < D) ? (v0 - mean) : 0.f;
    float ws2 = waveSum(dv * dv);
    if ((t & 63) == 0) red[4 + (t >> 6)] = ws2;
    __syncthreads();
    float rstd = rsqrtf((red[4] + red[5]) * (1.f / 128.f) + 1e-5f);
    if (t < D) xn[t] = dv * rstd * lnf_s[t] + lnf_b[t];
    __syncthreads();
    if (t < V) {
      float a = 0.f;
#pragma unroll 8
      for (int d = 0; d < D; ++d) a += xn[d] * hw[d * V + t];
      logits[row * V + t] = a + hb[t];
    }
    __syncthreads();
  }
}

// ---- per-position next-token log-likelihood ----
__global__ void kLL(const float* __restrict__ logits, const int* __restrict__ lat,
                    float* __restrict__ ll) {
  int p = blockIdx.x * blockDim.x + threadIdx.x;
  if (p >= L) return;
  const float* r = logits + p * V;
  float m = r[0];
#pragma unroll
  for (int v = 1; v < V; ++v) m = fmaxf(m, r[v]);
  float s = 0.f;
#pragma unroll
  for (int v = 0; v < V; ++v) s += expf(r[v] - m);
  float lse = m + logf(s);
  ll[p] = r[lat[p + 1]] - lse;
}

// ---- sort ll, 3% quantile, build heal list + chunk bounds ----
__global__ void kSort(const float* __restrict__ ll, int* __restrict__ heal_row,
                      int* __restrict__ bounds) {
  __shared__ float s[L];
  int t = threadIdx.x;
  for (int i = t; i < L; i += 256) s[i] = ll[i];
  __syncthreads();
  for (int ksz = 2; ksz <= L; ksz <<= 1) {
    for (int j = ksz >> 1; j > 0; j >>= 1) {
      for (int i = t; i < L; i += 256) {
        int lidx = i ^ j;
        if (lidx > i) {
          bool up = ((i & ksz) == 0);
          float a = s[i], b = s[lidx];
          if ((a > b) == up) { s[i] = b; s[lidx] = a; }
        }
      }
      __syncthreads();
    }
  }
  if (t == 0) {
    double frac = 0.03 * 1023.0 - 30.0;  // 0.69
    float val = (float)((double)s[30] + frac * ((double)s[31] - (double)s[30]));
    int rows[NHEAL];
    int c = 0;
    for (int p = 0; p < L; ++p) {
      if (ll[p] < val) {
        if (c < NHEAL) rows[c] = p;
        ++c;
      }
    }
    if (c > NHEAL) c = NHEAL;
    for (int k = 0; k < NHEAL; ++k) {
      if (k < c) {
        heal_row[k] = rows[k];
        bounds[2 * k] = (k == 0) ? 1 : (rows[k - 1] + 1);  // chunk 0 never launched
        bounds[2 * k + 1] = (k == 0) ? 0 : rows[k];
      } else {
        heal_row[k] = -1;
        bounds[2 * k] = 1;
        bounds[2 * k + 1] = 0;
      }
    }
    heal_row[NHEAL] = -1;
    bounds[2 * NHEAL] = (c > 0) ? (rows[c - 1] + 1) : L;  // final tail chunk
    bounds[2 * NHEAL + 1] = L - 1;
  }
}

// ---- heal: argmax over logits row (excluding BOS), write lat ----
__global__ void kHeal(const float* __restrict__ logits, const int* __restrict__ heal_row,
                      int* __restrict__ lat, int k) {
  if (threadIdx.x != 0) return;
  int r = heal_row[k];
  if (r < 0) return;
  const float* row = logits + r * V;
  int best = 0;
  float bv = row[0];
  for (int v = 1; v < BOSX; ++v) {  // exclude v == BOS (16)
    if (row[v] > bv) { bv = row[v]; best = v; }
  }
  lat[r + 1] = best;
}

// ---- write healed tokens as float to d_out tail ----
__global__ void kTokens(const int* __restrict__ lat, float* __restrict__ out) {
  int i = blockIdx.x * blockDim.x + threadIdx.x;
  if (i < L) out[i] = (float)lat[i + 1];
}

extern "C" void kernel_launch(void* const* d_in, const int* in_sizes, int n_in,
                              void* d_out, int out_size, void* d_ws, size_t ws_size,
                              hipStream_t stream) {
  const int* tokens  = (const int*)d_in[0];
  const float* emb   = (const float*)d_in[1];
  const float* pos   = (const float*)d_in[2];
  const float* ln1_s = (const float*)d_in[3];
  const float* ln1_b = (const float*)d_in[4];
  const float* wqkv  = (const float*)d_in[5];
  const float* bqkv  = (const float*)d_in[6];
  const float* wo    = (const float*)d_in[7];
  const float* bo    = (const float*)d_in[8];
  const float* ln2_s = (const float*)d_in[9];
  const float* ln2_b = (const float*)d_in[10];
  const float* w1    = (const float*)d_in[11];
  const float* b1    = (const float*)d_in[12];
  const float* w2    = (const float*)d_in[13];
  const float* b2    = (const float*)d_in[14];
  const float* lnf_s = (const float*)d_in[15];
  const float* lnf_b = (const float*)d_in[16];
  const float* hw    = (const float*)d_in[17];
  const float* hb    = (const float*)d_in[18];

  // workspace layout (floats)
  float* h    = (float*)d_ws;              // L*D
  float* qbuf = h + L * D;                 // L*D
  float* kc   = qbuf + L * D;              // NLAYER*L*D
  float* vc   = kc + NLAYER * L * D;       // NLAYER*L*D
  float* ll   = vc + NLAYER * L * D;       // L
  int* lat    = (int*)(ll + L);            // 1025 (pad 1032)
  int* heal_row = lat + 1032;              // 32
  int* bounds   = heal_row + 32;           // 64

  float* logits = (float*)d_out;           // L*V
  float* out_tok = logits + L * V;         // L

  kInit<<<5, 256, 0, stream>>>(tokens, lat);

  // ---- Phase A: full pass ----
  kEmbedRows<<<256, 128, 0, stream>>>(lat, emb, pos, h, bounds, -1);
  for (int l = 0; l < NLAYER; ++l) {
    kA<<<256, 256, 0, stream>>>(h, ln1_s + l * D, ln1_b + l * D, wqkv + l * D * 3 * D,
                                bqkv + l * 3 * D, qbuf, kc + l * L * D, vc + l * L * D,
                                bounds, -1);
    kB<<<256, 256, 0, stream>>>(h, qbuf, kc + l * L * D, vc + l * L * D, wo + l * D * D,
                                bo + l * D, ln2_s + l * D, ln2_b + l * D,
                                w1 + l * D * 4 * D, b1 + l * 4 * D, w2 + l * 4 * D * D,
                                b2 + l * D, bounds, -1);
  }
  kHead<<<256, 256, 0, stream>>>(h, lnf_s, lnf_b, hw, hb, logits, bounds, -1);
  kLL<<<4, 256, 0, stream>>>(logits, lat, ll);
  kSort<<<1, 256, 0, stream>>>(ll, heal_row, bounds);

  // ---- heal 0 uses Phase A logits directly ----
  kHeal<<<1, 64, 0, stream>>>(logits, heal_row, lat, 0);

  // ---- heals 1..30: chunked KV-cache recompute ----
  for (int k = 1; k < NHEAL; ++k) {
    kEmbedRows<<<128, 128, 0, stream>>>(lat, emb, pos, h, bounds, k);
    for (int l = 0; l < NLAYER; ++l) {
      kA<<<128, 256, 0, stream>>>(h, ln1_s + l * D, ln1_b + l * D, wqkv + l * D * 3 * D,
                                  bqkv + l * 3 * D, qbuf, kc + l * L * D, vc + l * L * D,
                                  bounds, k);
      kB<<<128, 256, 0, stream>>>(h, qbuf, kc + l * L * D, vc + l * L * D, wo + l * D * D,
                                  bo + l * D, ln2_s + l * D, ln2_b + l * D,
                                  w1 + l * D * 4 * D, b1 + l * 4 * D, w2 + l * 4 * D * D,
                                  b2 + l * D, bounds, k);
    }
    kHead<<<128, 256, 0, stream>>>(h, lnf_s, lnf_b, hw, hb, logits, bounds, k);
    kHeal<<<1, 64, 0, stream>>>(logits, heal_row, lat, k);
  }

  // ---- final tail chunk (rows after last heal) ----
  kEmbedRows<<<128, 128, 0, stream>>>(lat, emb, pos, h, bounds, NHEAL);
  for (int l = 0; l < NLAYER; ++l) {
    kA<<<128, 256, 0, stream>>>(h, ln1_s + l * D, ln1_b + l * D, wqkv + l * D * 3 * D,
                                bqkv + l * 3 * D, qbuf, kc + l * L * D, vc + l * L * D,
                                bounds, NHEAL);
    kB<<<128, 256, 0, stream>>>(h, qbuf, kc + l * L * D, vc + l * L * D, wo + l * D * D,
                                bo + l * D, ln2_s + l * D, ln2_b + l * D,
                                w1 + l * D * 4 * D, b1 + l * 4 * D, w2 + l * 4 * D * D,
                                b2 + l * D, bounds, NHEAL);
  }
  kHead<<<128, 256, 0, stream>>>(h, lnf_s, lnf_b, hw, hb, logits, bounds, NHEAL);

  kTokens<<<4, 256, 0, stream>>>(lat, out_tok);
}